// Round 11
// baseline (100.536 us; speedup 1.0000x reference)
//
#include <hip/hip_runtime.h>
#include <hip/hip_fp16.h>

// StructuralGcn: 3-layer GCN, N=50000 nodes, E=800000 edges (+ self loops).
// Round 10 -> 11: agg kernels pay ~35% wave divergence: 8/16/32 nodes share a
// wave and the edge loop runs to max(deg) of the group (Poisson(16) -> E[max8]
// ~23 vs mean 16). Fix: per-bucket counting sort by degree in local_fill ->
// perm[]; agg kernels process nodes in degree-sorted order so co-wave nodes
// have ~equal degree. Also esrc stored as ushort (src < 2^16): halves edge
// index traffic. Per-node summation order unchanged -> absmax identical.

#define IN_C 128
#define NPB_SHIFT 8            // 256 nodes per bucket
#define BCAP 5120              // per-bucket edge capacity (mean 4096, ~16 sigma)

static __device__ __forceinline__ float2 up2(unsigned u) {
    __half2 h = *reinterpret_cast<__half2*>(&u);
    return __half22float2(h);
}
static __device__ __forceinline__ unsigned pk2(float a, float b) {
    __half2 h = __floats2half2_rn(a, b);
    return *reinterpret_cast<unsigned*>(&h);
}
static __device__ __forceinline__ int wave_incl_scan(int v, int lane) {
#pragma unroll
    for (int off = 1; off < 64; off <<= 1) {
        const int u = __shfl_up(v, off);
        if (lane >= off) v += u;
    }
    return v;
}

#define ACC8(v) { float2 f_; \
    f_ = up2((v).x); a[0] += f_.x; a[1] += f_.y; \
    f_ = up2((v).y); a[2] += f_.x; a[3] += f_.y; \
    f_ = up2((v).z); a[4] += f_.x; a[5] += f_.y; \
    f_ = up2((v).w); a[6] += f_.x; a[7] += f_.y; }

// ---------------- tiny init ----------------

__global__ void zero256_kernel(int* __restrict__ p) { p[threadIdx.x] = 0; }

// ---------------- pass 1: block-local counting sort by bucket ----------------

__global__ __launch_bounds__(256) void partition_kernel(
    const int* __restrict__ src, const int* __restrict__ dst,
    int* __restrict__ bucketcur, unsigned* __restrict__ tmp, int n_edges, int nb) {
    constexpr int EPT = 8;
    __shared__ int hist[256];
    __shared__ int excl[256];
    __shared__ int rankc[256];
    __shared__ int gbase[256];
    __shared__ int wsum[4];
    __shared__ unsigned sorted[256 * EPT];   // 8 KB

    const int t = threadIdx.x;
    const int lane = t & 63;
    const int w = t >> 6;
    const int e0 = blockIdx.x * 256 * EPT;
    hist[t] = 0;
    rankc[t] = 0;
    __syncthreads();

    int d[EPT], s[EPT];
#pragma unroll
    for (int i = 0; i < EPT; ++i) {
        const int e = e0 + t + i * 256;      // coalesced
        if (e < n_edges) {
            d[i] = dst[e];
            s[i] = src[e];
            atomicAdd(&hist[d[i] >> NPB_SHIFT], 1);
        } else {
            d[i] = -1;
        }
    }
    __syncthreads();

    const int hv = hist[t];
    const int inc = wave_incl_scan(hv, lane);
    if (lane == 63) wsum[w] = inc;
    __syncthreads();
    int base = 0;
#pragma unroll
    for (int i = 0; i < 4; ++i)
        if (i < w) base += wsum[i];
    excl[t] = base + inc - hv;               // exclusive prefix
    if (t < nb && hv > 0) gbase[t] = t * BCAP + atomicAdd(&bucketcur[t], hv);
    __syncthreads();

#pragma unroll
    for (int i = 0; i < EPT; ++i) {
        if (d[i] >= 0) {
            const int b = d[i] >> NPB_SHIFT;
            const int r = atomicAdd(&rankc[b], 1);
            sorted[excl[b] + r] = ((unsigned)d[i] << 16) | (unsigned)s[i];
        }
    }
    __syncthreads();

    const int m = min(256 * EPT, n_edges - e0);
    for (int i = t; i < m; i += 256) {
        const unsigned pk = sorted[i];
        const int b = (int)(pk >> 24);       // dst>>8
        tmp[gbase[b] + (i - excl[b])] = pk;
    }
}

// ---------------- pass 2: per-bucket CSR build + fill + degree sort ----------

__global__ __launch_bounds__(256) void local_fill_kernel(
    const unsigned* __restrict__ tmp, const int* __restrict__ bucketcur,
    int* __restrict__ row_start, int* __restrict__ deg, float* __restrict__ dinv,
    int* __restrict__ perm, unsigned short* __restrict__ esrc, int n_nodes) {
    __shared__ int histl[256];
    __shared__ int cur[256];
    __shared__ int wsum[4];
    __shared__ int dhist[64];
    __shared__ int dexcl[64];
    __shared__ int dcur[64];
    __shared__ unsigned eb[BCAP];            // 20 KB bucket cache
    const int b = blockIdx.x;
    const int base = b * BCAP;
    const int t = threadIdx.x;
    const int lane = t & 63;
    const int w = t >> 6;
    const int m = min(bucketcur[b], BCAP);
    histl[t] = 0;
    if (t < 64) { dhist[t] = 0; dcur[t] = 0; }
    __syncthreads();

    for (int i = t; i < m; i += 256) {
        const unsigned p = tmp[base + i];
        eb[i] = p;
        atomicAdd(&histl[(p >> 16) & 255u], 1);
    }
    __syncthreads();

    const int hv = histl[t];
    const int inc = wave_incl_scan(hv, lane);
    if (lane == 63) wsum[w] = inc;
    __syncthreads();
    int wb = 0;
#pragma unroll
    for (int i = 0; i < 4; ++i)
        if (i < w) wb += wsum[i];
    const int rs = base + wb + inc - hv;     // exclusive + bucket base
    const int node = (b << NPB_SHIFT) + t;
    const int bin = min(hv, 63);
    if (node < n_nodes) {
        row_start[node] = rs;
        deg[node] = hv;
        dinv[node] = rsqrtf((float)hv + 1.0f);   // +1 = self loop
        atomicAdd(&dhist[bin], 1);
    }
    cur[t] = rs;
    __syncthreads();

    // degree-bin exclusive scan (wave 0) + rank -> per-bucket perm
    if (t < 64) {
        const int v = dhist[t];
        dexcl[t] = wave_incl_scan(v, t) - v;
    }
    __syncthreads();
    if (node < n_nodes) {
        const int r = atomicAdd(&dcur[bin], 1);
        perm[(b << NPB_SHIFT) + dexcl[bin] + r] = node;
    }

    for (int i = t; i < m; i += 256) {
        const unsigned p = eb[i];
        const int pos = atomicAdd(&cur[(p >> 16) & 255u], 1);
        esrc[pos] = (unsigned short)(p & 0xFFFFu);
    }
}

// ---------------- layer-1 GEMM: g1h = half((x @ W1) * dinv) ----------------

__global__ __launch_bounds__(256) void gemm1_kernel(
    const float* __restrict__ x, const float* __restrict__ W,
    const float* __restrict__ dinv, __half* __restrict__ g1h, int n_nodes) {
    constexpr int KDIM = 128, COUT = 64;
    __shared__ float Wl[KDIM * COUT];
    const int tid = threadIdx.x;
#pragma unroll
    for (int i = 0; i < KDIM * COUT / 1024; ++i) {
        const int idx = (i * 256 + tid) * 4;
        *(float4*)&Wl[idx] = *(const float4*)&W[idx];
    }
    __syncthreads();

    const int tx = tid % 16;
    const int ty = tid / 16;
    const int c0 = tx * 4;
    const int n0 = blockIdx.x * 64 + ty * 4;

    const float4* xr[4];
#pragma unroll
    for (int nn = 0; nn < 4; ++nn) {
        const int node = n0 + nn;
        xr[nn] = (const float4*)(x + (size_t)(node < n_nodes ? node : 0) * KDIM);
    }

    float acc[4][4] = {};
#pragma unroll 4
    for (int k4 = 0; k4 < KDIM / 4; ++k4) {
        float4 xv[4], wv[4];
#pragma unroll
        for (int nn = 0; nn < 4; ++nn) xv[nn] = xr[nn][k4];
#pragma unroll
        for (int kk = 0; kk < 4; ++kk)
            wv[kk] = *(const float4*)&Wl[(k4 * 4 + kk) * COUT + c0];
#pragma unroll
        for (int nn = 0; nn < 4; ++nn) {
            const float xs0 = xv[nn].x, xs1 = xv[nn].y, xs2 = xv[nn].z, xs3 = xv[nn].w;
            acc[nn][0] = fmaf(xs0, wv[0].x, fmaf(xs1, wv[1].x, fmaf(xs2, wv[2].x, fmaf(xs3, wv[3].x, acc[nn][0]))));
            acc[nn][1] = fmaf(xs0, wv[0].y, fmaf(xs1, wv[1].y, fmaf(xs2, wv[2].y, fmaf(xs3, wv[3].y, acc[nn][1]))));
            acc[nn][2] = fmaf(xs0, wv[0].z, fmaf(xs1, wv[1].z, fmaf(xs2, wv[2].z, fmaf(xs3, wv[3].z, acc[nn][2]))));
            acc[nn][3] = fmaf(xs0, wv[0].w, fmaf(xs1, wv[1].w, fmaf(xs2, wv[2].w, fmaf(xs3, wv[3].w, acc[nn][3]))));
        }
    }

#pragma unroll
    for (int nn = 0; nn < 4; ++nn) {
        const int node = n0 + nn;
        if (node < n_nodes) {
            const float dv = dinv[node];
            uint2 pk;
            pk.x = pk2(acc[nn][0] * dv, acc[nn][1] * dv);
            pk.y = pk2(acc[nn][2] * dv, acc[nn][3] * dv);
            *(uint2*)&g1h[(size_t)node * COUT + c0] = pk;
        }
    }
}

// ---------------- agg64: z1h = half(relu(dinv*(sum + self) + b1)) ----------
// 8 lanes per node, nodes taken in degree-sorted perm order (uniform loop
// trip count within a wave). Lane owns 8 channels (uint4 slice), zero
// cross-lane ops.

__global__ __launch_bounds__(256) void agg64_kernel(
    const int* __restrict__ row_start, const int* __restrict__ deg,
    const int* __restrict__ perm, const unsigned short* __restrict__ esrc,
    const __half* __restrict__ g1h, const float* __restrict__ dinv,
    const float* __restrict__ b1, __half* __restrict__ z1h, int n) {
    const int t = threadIdx.x;
    const int lane = t & 63;
    const int c4 = lane & 7;                 // uint4 slice within row
    const int pos = blockIdx.x * 32 + (t >> 6) * 8 + (lane >> 3);
    if (pos >= n) return;
    const int node = perm[pos];
    const uint4* __restrict__ tab = (const uint4*)g1h;   // 8 uint4 per row
    const int beg = row_start[node];
    const int dg = deg[node];

    float a[8] = {};
    int i = 0;
    if (dg >= 8) {
        int s0 = esrc[beg], s1 = esrc[beg + 1], s2 = esrc[beg + 2], s3 = esrc[beg + 3];
        for (; i + 8 <= dg; i += 4) {
            const int t0 = esrc[beg + i + 4], t1 = esrc[beg + i + 5],
                      t2 = esrc[beg + i + 6], t3 = esrc[beg + i + 7];
            const uint4 v0 = tab[(size_t)s0 * 8 + c4];
            const uint4 v1 = tab[(size_t)s1 * 8 + c4];
            const uint4 v2 = tab[(size_t)s2 * 8 + c4];
            const uint4 v3 = tab[(size_t)s3 * 8 + c4];
            ACC8(v0); ACC8(v1); ACC8(v2); ACC8(v3);
            s0 = t0; s1 = t1; s2 = t2; s3 = t3;
        }
        const uint4 v0 = tab[(size_t)s0 * 8 + c4];
        const uint4 v1 = tab[(size_t)s1 * 8 + c4];
        const uint4 v2 = tab[(size_t)s2 * 8 + c4];
        const uint4 v3 = tab[(size_t)s3 * 8 + c4];
        ACC8(v0); ACC8(v1); ACC8(v2); ACC8(v3);
        i += 4;
    }
    for (; i + 4 <= dg; i += 4) {
        const int s0 = esrc[beg + i], s1 = esrc[beg + i + 1],
                  s2 = esrc[beg + i + 2], s3 = esrc[beg + i + 3];
        const uint4 v0 = tab[(size_t)s0 * 8 + c4];
        const uint4 v1 = tab[(size_t)s1 * 8 + c4];
        const uint4 v2 = tab[(size_t)s2 * 8 + c4];
        const uint4 v3 = tab[(size_t)s3 * 8 + c4];
        ACC8(v0); ACC8(v1); ACC8(v2); ACC8(v3);
    }
    for (; i < dg; ++i) {
        const uint4 v = tab[(size_t)esrc[beg + i] * 8 + c4];
        ACC8(v);
    }

    const float dv = dinv[node];
    const uint4 sv = tab[(size_t)node * 8 + c4];
    const float2 f0 = up2(sv.x), f1 = up2(sv.y), f2 = up2(sv.z), f3 = up2(sv.w);
    const float4 bb0 = ((const float4*)b1)[c4 * 2];
    const float4 bb1 = ((const float4*)b1)[c4 * 2 + 1];
    uint4 o;
    o.x = pk2(fmaxf(dv * (a[0] + f0.x) + bb0.x, 0.0f),
              fmaxf(dv * (a[1] + f0.y) + bb0.y, 0.0f));
    o.y = pk2(fmaxf(dv * (a[2] + f1.x) + bb0.z, 0.0f),
              fmaxf(dv * (a[3] + f1.y) + bb0.w, 0.0f));
    o.z = pk2(fmaxf(dv * (a[4] + f2.x) + bb1.x, 0.0f),
              fmaxf(dv * (a[5] + f2.y) + bb1.y, 0.0f));
    o.w = pk2(fmaxf(dv * (a[6] + f3.x) + bb1.z, 0.0f),
              fmaxf(dv * (a[7] + f3.y) + bb1.w, 0.0f));
    ((uint4*)z1h)[(size_t)node * 8 + c4] = o;
}

// ---------------- gemm2: g2h = half((z1h @ W2) * dinv) ----------------

__global__ __launch_bounds__(256) void gemm2_kernel(
    const __half* __restrict__ z1h, const float* __restrict__ W2,
    const float* __restrict__ dinv, __half* __restrict__ g2h, int n_nodes) {
    __shared__ float Wl[64 * 32];
    const int tid = threadIdx.x;
    {
        const float4* Ws = (const float4*)W2;
        float4* Wd = (float4*)Wl;
        Wd[tid] = Ws[tid];
        Wd[tid + 256] = Ws[tid + 256];
    }
    __syncthreads();

    const int tx = tid & 7;
    const int ty = tid >> 3;
    const int c0 = tx * 4;
    const int n0 = blockIdx.x * 128 + ty * 4;

    const uint2* xr[4];
#pragma unroll
    for (int nn = 0; nn < 4; ++nn) {
        const int node = n0 + nn;
        xr[nn] = (const uint2*)(z1h + (size_t)(node < n_nodes ? node : 0) * 64);
    }

    float acc[4][4] = {};
#pragma unroll 4
    for (int k4 = 0; k4 < 16; ++k4) {
        float4 wv[4];
#pragma unroll
        for (int kk = 0; kk < 4; ++kk)
            wv[kk] = *(const float4*)&Wl[(k4 * 4 + kk) * 32 + c0];
#pragma unroll
        for (int nn = 0; nn < 4; ++nn) {
            const uint2 xv = xr[nn][k4];
            const float2 xlo = up2(xv.x), xhi = up2(xv.y);
            acc[nn][0] = fmaf(xlo.x, wv[0].x, fmaf(xlo.y, wv[1].x, fmaf(xhi.x, wv[2].x, fmaf(xhi.y, wv[3].x, acc[nn][0]))));
            acc[nn][1] = fmaf(xlo.x, wv[0].y, fmaf(xlo.y, wv[1].y, fmaf(xhi.x, wv[2].y, fmaf(xhi.y, wv[3].y, acc[nn][1]))));
            acc[nn][2] = fmaf(xlo.x, wv[0].z, fmaf(xlo.y, wv[1].z, fmaf(xhi.x, wv[2].z, fmaf(xhi.y, wv[3].z, acc[nn][2]))));
            acc[nn][3] = fmaf(xlo.x, wv[0].w, fmaf(xlo.y, wv[1].w, fmaf(xhi.x, wv[2].w, fmaf(xhi.y, wv[3].w, acc[nn][3]))));
        }
    }

#pragma unroll
    for (int nn = 0; nn < 4; ++nn) {
        const int node = n0 + nn;
        if (node < n_nodes) {
            const float dv = dinv[node];
            uint2 o;
            o.x = pk2(acc[nn][0] * dv, acc[nn][1] * dv);
            o.y = pk2(acc[nn][2] * dv, acc[nn][3] * dv);
            *(uint2*)&g2h[(size_t)node * 32 + c0] = o;
        }
    }
}

// ---------------- agg32 + gemm3: g3 = (relu(...) . W3) * dinv ----------
// 4 lanes per node, degree-sorted perm order; lane owns 8 channels.

__global__ __launch_bounds__(256) void agg32_gemm3_kernel(
    const int* __restrict__ row_start, const int* __restrict__ deg,
    const int* __restrict__ perm, const unsigned short* __restrict__ esrc,
    const __half* __restrict__ g2h, const float* __restrict__ dinv,
    const float* __restrict__ b2, const float* __restrict__ W3,
    float* __restrict__ g3, int n) {
    const int t = threadIdx.x;
    const int lane = t & 63;
    const int c2 = lane & 3;                 // uint4 slice within row
    const int pos = blockIdx.x * 64 + (t >> 6) * 16 + (lane >> 2);
    if (pos >= n) return;
    const int node = perm[pos];
    const uint4* __restrict__ tab = (const uint4*)g2h;   // 4 uint4 per row
    const int beg = row_start[node];
    const int dg = deg[node];

    float a[8] = {};
    int i = 0;
    if (dg >= 8) {
        int s0 = esrc[beg], s1 = esrc[beg + 1], s2 = esrc[beg + 2], s3 = esrc[beg + 3];
        for (; i + 8 <= dg; i += 4) {
            const int t0 = esrc[beg + i + 4], t1 = esrc[beg + i + 5],
                      t2 = esrc[beg + i + 6], t3 = esrc[beg + i + 7];
            const uint4 v0 = tab[(size_t)s0 * 4 + c2];
            const uint4 v1 = tab[(size_t)s1 * 4 + c2];
            const uint4 v2 = tab[(size_t)s2 * 4 + c2];
            const uint4 v3 = tab[(size_t)s3 * 4 + c2];
            ACC8(v0); ACC8(v1); ACC8(v2); ACC8(v3);
            s0 = t0; s1 = t1; s2 = t2; s3 = t3;
        }
        const uint4 v0 = tab[(size_t)s0 * 4 + c2];
        const uint4 v1 = tab[(size_t)s1 * 4 + c2];
        const uint4 v2 = tab[(size_t)s2 * 4 + c2];
        const uint4 v3 = tab[(size_t)s3 * 4 + c2];
        ACC8(v0); ACC8(v1); ACC8(v2); ACC8(v3);
        i += 4;
    }
    for (; i + 4 <= dg; i += 4) {
        const int s0 = esrc[beg + i], s1 = esrc[beg + i + 1],
                  s2 = esrc[beg + i + 2], s3 = esrc[beg + i + 3];
        const uint4 v0 = tab[(size_t)s0 * 4 + c2];
        const uint4 v1 = tab[(size_t)s1 * 4 + c2];
        const uint4 v2 = tab[(size_t)s2 * 4 + c2];
        const uint4 v3 = tab[(size_t)s3 * 4 + c2];
        ACC8(v0); ACC8(v1); ACC8(v2); ACC8(v3);
    }
    for (; i < dg; ++i) {
        const uint4 v = tab[(size_t)esrc[beg + i] * 4 + c2];
        ACC8(v);
    }

    const float dv = dinv[node];
    const uint4 sv = tab[(size_t)node * 4 + c2];
    const float2 f0 = up2(sv.x), f1 = up2(sv.y), f2 = up2(sv.z), f3 = up2(sv.w);
    const float4 bb0 = ((const float4*)b2)[c2 * 2];
    const float4 bb1 = ((const float4*)b2)[c2 * 2 + 1];
    const float4 w0 = ((const float4*)W3)[c2 * 2];
    const float4 w1 = ((const float4*)W3)[c2 * 2 + 1];
    float p = 0.0f;
    p = fmaf(fmaxf(dv * (a[0] + f0.x) + bb0.x, 0.0f), w0.x, p);
    p = fmaf(fmaxf(dv * (a[1] + f0.y) + bb0.y, 0.0f), w0.y, p);
    p = fmaf(fmaxf(dv * (a[2] + f1.x) + bb0.z, 0.0f), w0.z, p);
    p = fmaf(fmaxf(dv * (a[3] + f1.y) + bb0.w, 0.0f), w0.w, p);
    p = fmaf(fmaxf(dv * (a[4] + f2.x) + bb1.x, 0.0f), w1.x, p);
    p = fmaf(fmaxf(dv * (a[5] + f2.y) + bb1.y, 0.0f), w1.y, p);
    p = fmaf(fmaxf(dv * (a[6] + f3.x) + bb1.z, 0.0f), w1.z, p);
    p = fmaf(fmaxf(dv * (a[7] + f3.y) + bb1.w, 0.0f), w1.w, p);
    p += __shfl_xor(p, 1);
    p += __shfl_xor(p, 2);
    if (c2 == 0) g3[node] = p * dv;
}

// ---------------- layer-3 aggregation (degree-sorted) ----------------

__global__ __launch_bounds__(256) void agg_kernel1(
    const int* __restrict__ row_start, const int* __restrict__ deg,
    const int* __restrict__ perm, const unsigned short* __restrict__ esrc,
    const float* __restrict__ g, const float* __restrict__ dinv,
    const float* __restrict__ b3, float* __restrict__ out, int n) {
    const int pos = blockIdx.x * 32 + (threadIdx.x >> 3);
    if (pos >= n) return;
    const int node = perm[pos];
    const int l = threadIdx.x & 7;
    const int beg = row_start[node], end = beg + deg[node];
    float acc = 0.0f;
    for (int e = beg + l; e < end; e += 8)
        acc += g[esrc[e]];
    acc += __shfl_xor(acc, 1);
    acc += __shfl_xor(acc, 2);
    acc += __shfl_xor(acc, 4);
    if (l == 0) out[node] = dinv[node] * (acc + g[node]) + b3[0];
}

// ---------------- launcher ----------------

extern "C" void kernel_launch(void* const* d_in, const int* in_sizes, int n_in,
                              void* d_out, int out_size, void* d_ws, size_t ws_size,
                              hipStream_t stream) {
    const float* x  = (const float*)d_in[0];
    const int*   ei = (const int*)d_in[1];
    const float* W1 = (const float*)d_in[2];
    const float* b1 = (const float*)d_in[3];
    const float* W2 = (const float*)d_in[4];
    const float* b2 = (const float*)d_in[5];
    const float* W3 = (const float*)d_in[6];
    const float* b3 = (const float*)d_in[7];
    float* out = (float*)d_out;

    const int n_nodes = in_sizes[0] / IN_C;    // 50000
    const int n_edges = in_sizes[1] / 2;       // 800000
    const int* src = ei;
    const int* dst = ei + n_edges;
    const int nbuckets = (n_nodes + (1 << NPB_SHIFT) - 1) >> NPB_SHIFT;  // 196

    auto align_up = [](size_t v) { return (v + 255) & ~(size_t)255; };
    char* p = (char*)d_ws;
    int*            bucketcur = (int*)p;            p += align_up(256 * 4);
    int*            row_start = (int*)p;            p += align_up((size_t)n_nodes * 4);
    int*            deg       = (int*)p;            p += align_up((size_t)n_nodes * 4);
    float*          dinv      = (float*)p;          p += align_up((size_t)n_nodes * 4);
    int*            perm      = (int*)p;            p += align_up((size_t)n_nodes * 4);
    unsigned short* esrc      = (unsigned short*)p; p += align_up((size_t)nbuckets * BCAP * 2);
    __half*         g1h       = (__half*)p;         p += align_up((size_t)n_nodes * 64 * 2);
    __half*         z1h       = (__half*)p;         p += align_up((size_t)n_nodes * 64 * 2);
    // union region: tmp (CSR build only) overlaid by g2h/g3 (layers 2/3)
    char* up = p;
    unsigned*       tmp       = (unsigned*)up;      // nbuckets*BCAP*4 ~ 4MB
    __half*         g2h       = (__half*)up;        // 3.2 MB
    float*          g3        = (float*)(up + align_up((size_t)n_nodes * 32 * 2));
    (void)ws_size; (void)n_in; (void)out_size;

    // CSR build (bucketed, no global scan) + degree-sorted perm
    zero256_kernel<<<1, 256, 0, stream>>>(bucketcur);
    partition_kernel<<<(n_edges + 2047) / 2048, 256, 0, stream>>>(src, dst, bucketcur, tmp, n_edges, nbuckets);
    local_fill_kernel<<<nbuckets, 256, 0, stream>>>(tmp, bucketcur, row_start, deg, dinv, perm, esrc, n_nodes);

    // layer 1: 128 -> 64 (g1h), agg (shuffle-free) -> z1h, dense gemm2 -> g2h
    gemm1_kernel<<<(n_nodes + 63) / 64, 256, 0, stream>>>(x, W1, dinv, g1h, n_nodes);
    agg64_kernel<<<(n_nodes + 31) / 32, 256, 0, stream>>>(row_start, deg, perm, esrc, g1h, dinv, b1, z1h, n_nodes);
    gemm2_kernel<<<(n_nodes + 127) / 128, 256, 0, stream>>>(z1h, W2, dinv, g2h, n_nodes);

    // layer 2: agg (shuffle-free) + relu + dot(W3) -> g3
    agg32_gemm3_kernel<<<(n_nodes + 63) / 64, 256, 0, stream>>>(row_start, deg, perm, esrc, g2h, dinv, b2, W3, g3, n_nodes);

    // layer 3: aggregate g3 -> out
    agg_kernel1<<<(n_nodes + 31) / 32, 256, 0, stream>>>(row_start, deg, perm, esrc, g3, dinv, b3, out, n_nodes);
}

// Round 12
// 93.118 us; speedup vs baseline: 1.0797x; 1.0797x over previous
//
#include <hip/hip_runtime.h>
#include <hip/hip_fp16.h>

// StructuralGcn: 3-layer GCN, N=50000 nodes, E=800000 edges (+ self loops).
// Round 11 -> 12: R11's degree-sorted perm REGRESSED (+5.3us): the indirection
// scattered self-loop reads, z1h writes (was contiguous 1KB/wave), and esrc
// streaming -- costing more than the divergence it recovered. Reverted to the
// R10 consecutive-node layout; kept only the orthogonal safe piece: esrc as
// ushort (halves index footprint 3.2->1.6MB, frees L2 for the gather table).

#define IN_C 128
#define NPB_SHIFT 8            // 256 nodes per bucket
#define BCAP 5120              // per-bucket edge capacity (mean 4096, ~16 sigma)

static __device__ __forceinline__ float2 up2(unsigned u) {
    __half2 h = *reinterpret_cast<__half2*>(&u);
    return __half22float2(h);
}
static __device__ __forceinline__ unsigned pk2(float a, float b) {
    __half2 h = __floats2half2_rn(a, b);
    return *reinterpret_cast<unsigned*>(&h);
}
static __device__ __forceinline__ int wave_incl_scan(int v, int lane) {
#pragma unroll
    for (int off = 1; off < 64; off <<= 1) {
        const int u = __shfl_up(v, off);
        if (lane >= off) v += u;
    }
    return v;
}

#define ACC8(v) { float2 f_; \
    f_ = up2((v).x); a[0] += f_.x; a[1] += f_.y; \
    f_ = up2((v).y); a[2] += f_.x; a[3] += f_.y; \
    f_ = up2((v).z); a[4] += f_.x; a[5] += f_.y; \
    f_ = up2((v).w); a[6] += f_.x; a[7] += f_.y; }

// ---------------- tiny init ----------------

__global__ void zero256_kernel(int* __restrict__ p) { p[threadIdx.x] = 0; }

// ---------------- pass 1: block-local counting sort by bucket ----------------

__global__ __launch_bounds__(256) void partition_kernel(
    const int* __restrict__ src, const int* __restrict__ dst,
    int* __restrict__ bucketcur, unsigned* __restrict__ tmp, int n_edges, int nb) {
    constexpr int EPT = 8;
    __shared__ int hist[256];
    __shared__ int excl[256];
    __shared__ int rankc[256];
    __shared__ int gbase[256];
    __shared__ int wsum[4];
    __shared__ unsigned sorted[256 * EPT];   // 8 KB

    const int t = threadIdx.x;
    const int lane = t & 63;
    const int w = t >> 6;
    const int e0 = blockIdx.x * 256 * EPT;
    hist[t] = 0;
    rankc[t] = 0;
    __syncthreads();

    int d[EPT], s[EPT];
#pragma unroll
    for (int i = 0; i < EPT; ++i) {
        const int e = e0 + t + i * 256;      // coalesced
        if (e < n_edges) {
            d[i] = dst[e];
            s[i] = src[e];
            atomicAdd(&hist[d[i] >> NPB_SHIFT], 1);
        } else {
            d[i] = -1;
        }
    }
    __syncthreads();

    const int hv = hist[t];
    const int inc = wave_incl_scan(hv, lane);
    if (lane == 63) wsum[w] = inc;
    __syncthreads();
    int base = 0;
#pragma unroll
    for (int i = 0; i < 4; ++i)
        if (i < w) base += wsum[i];
    excl[t] = base + inc - hv;               // exclusive prefix
    if (t < nb && hv > 0) gbase[t] = t * BCAP + atomicAdd(&bucketcur[t], hv);
    __syncthreads();

#pragma unroll
    for (int i = 0; i < EPT; ++i) {
        if (d[i] >= 0) {
            const int b = d[i] >> NPB_SHIFT;
            const int r = atomicAdd(&rankc[b], 1);
            sorted[excl[b] + r] = ((unsigned)d[i] << 16) | (unsigned)s[i];
        }
    }
    __syncthreads();

    const int m = min(256 * EPT, n_edges - e0);
    for (int i = t; i < m; i += 256) {
        const unsigned pk = sorted[i];
        const int b = (int)(pk >> 24);       // dst>>8
        tmp[gbase[b] + (i - excl[b])] = pk;
    }
}

// ---------------- pass 2: per-bucket CSR build + fill (LDS-cached) ----------

__global__ __launch_bounds__(256) void local_fill_kernel(
    const unsigned* __restrict__ tmp, const int* __restrict__ bucketcur,
    int* __restrict__ row_start, int* __restrict__ deg, float* __restrict__ dinv,
    unsigned short* __restrict__ esrc, int n_nodes) {
    __shared__ int histl[256];
    __shared__ int cur[256];
    __shared__ int wsum[4];
    __shared__ unsigned eb[BCAP];            // 20 KB bucket cache
    const int b = blockIdx.x;
    const int base = b * BCAP;
    const int t = threadIdx.x;
    const int lane = t & 63;
    const int w = t >> 6;
    const int m = min(bucketcur[b], BCAP);
    histl[t] = 0;
    __syncthreads();

    for (int i = t; i < m; i += 256) {
        const unsigned p = tmp[base + i];
        eb[i] = p;
        atomicAdd(&histl[(p >> 16) & 255u], 1);
    }
    __syncthreads();

    const int hv = histl[t];
    const int inc = wave_incl_scan(hv, lane);
    if (lane == 63) wsum[w] = inc;
    __syncthreads();
    int wb = 0;
#pragma unroll
    for (int i = 0; i < 4; ++i)
        if (i < w) wb += wsum[i];
    const int rs = base + wb + inc - hv;     // exclusive + bucket base
    const int node = (b << NPB_SHIFT) + t;
    if (node < n_nodes) {
        row_start[node] = rs;
        deg[node] = hv;
        dinv[node] = rsqrtf((float)hv + 1.0f);   // +1 = self loop
    }
    cur[t] = rs;
    __syncthreads();

    for (int i = t; i < m; i += 256) {
        const unsigned p = eb[i];
        const int pos = atomicAdd(&cur[(p >> 16) & 255u], 1);
        esrc[pos] = (unsigned short)(p & 0xFFFFu);
    }
}

// ---------------- layer-1 GEMM: g1h = half((x @ W1) * dinv) ----------------

__global__ __launch_bounds__(256) void gemm1_kernel(
    const float* __restrict__ x, const float* __restrict__ W,
    const float* __restrict__ dinv, __half* __restrict__ g1h, int n_nodes) {
    constexpr int KDIM = 128, COUT = 64;
    __shared__ float Wl[KDIM * COUT];
    const int tid = threadIdx.x;
#pragma unroll
    for (int i = 0; i < KDIM * COUT / 1024; ++i) {
        const int idx = (i * 256 + tid) * 4;
        *(float4*)&Wl[idx] = *(const float4*)&W[idx];
    }
    __syncthreads();

    const int tx = tid % 16;
    const int ty = tid / 16;
    const int c0 = tx * 4;
    const int n0 = blockIdx.x * 64 + ty * 4;

    const float4* xr[4];
#pragma unroll
    for (int nn = 0; nn < 4; ++nn) {
        const int node = n0 + nn;
        xr[nn] = (const float4*)(x + (size_t)(node < n_nodes ? node : 0) * KDIM);
    }

    float acc[4][4] = {};
#pragma unroll 4
    for (int k4 = 0; k4 < KDIM / 4; ++k4) {
        float4 xv[4], wv[4];
#pragma unroll
        for (int nn = 0; nn < 4; ++nn) xv[nn] = xr[nn][k4];
#pragma unroll
        for (int kk = 0; kk < 4; ++kk)
            wv[kk] = *(const float4*)&Wl[(k4 * 4 + kk) * COUT + c0];
#pragma unroll
        for (int nn = 0; nn < 4; ++nn) {
            const float xs0 = xv[nn].x, xs1 = xv[nn].y, xs2 = xv[nn].z, xs3 = xv[nn].w;
            acc[nn][0] = fmaf(xs0, wv[0].x, fmaf(xs1, wv[1].x, fmaf(xs2, wv[2].x, fmaf(xs3, wv[3].x, acc[nn][0]))));
            acc[nn][1] = fmaf(xs0, wv[0].y, fmaf(xs1, wv[1].y, fmaf(xs2, wv[2].y, fmaf(xs3, wv[3].y, acc[nn][1]))));
            acc[nn][2] = fmaf(xs0, wv[0].z, fmaf(xs1, wv[1].z, fmaf(xs2, wv[2].z, fmaf(xs3, wv[3].z, acc[nn][2]))));
            acc[nn][3] = fmaf(xs0, wv[0].w, fmaf(xs1, wv[1].w, fmaf(xs2, wv[2].w, fmaf(xs3, wv[3].w, acc[nn][3]))));
        }
    }

#pragma unroll
    for (int nn = 0; nn < 4; ++nn) {
        const int node = n0 + nn;
        if (node < n_nodes) {
            const float dv = dinv[node];
            uint2 pk;
            pk.x = pk2(acc[nn][0] * dv, acc[nn][1] * dv);
            pk.y = pk2(acc[nn][2] * dv, acc[nn][3] * dv);
            *(uint2*)&g1h[(size_t)node * COUT + c0] = pk;
        }
    }
}

// ---------------- agg64: z1h = half(relu(dinv*(sum + self) + b1)) ----------
// 8 lanes per node (8 consecutive nodes/wave); lane owns 8 channels (uint4).
// Zero cross-lane ops; 4 rows (4x dwordx4) in flight per node.

__global__ __launch_bounds__(256) void agg64_kernel(
    const int* __restrict__ row_start, const int* __restrict__ deg,
    const unsigned short* __restrict__ esrc, const __half* __restrict__ g1h,
    const float* __restrict__ dinv, const float* __restrict__ b1,
    __half* __restrict__ z1h, int n) {
    const int t = threadIdx.x;
    const int lane = t & 63;
    const int c4 = lane & 7;                 // uint4 slice within row
    const int node = blockIdx.x * 32 + (t >> 6) * 8 + (lane >> 3);
    if (node >= n) return;
    const uint4* __restrict__ tab = (const uint4*)g1h;   // 8 uint4 per row
    const int beg = row_start[node];
    const int dg = deg[node];

    float a[8] = {};
    int i = 0;
    if (dg >= 8) {
        int s0 = esrc[beg], s1 = esrc[beg + 1], s2 = esrc[beg + 2], s3 = esrc[beg + 3];
        for (; i + 8 <= dg; i += 4) {
            const int t0 = esrc[beg + i + 4], t1 = esrc[beg + i + 5],
                      t2 = esrc[beg + i + 6], t3 = esrc[beg + i + 7];
            const uint4 v0 = tab[(size_t)s0 * 8 + c4];
            const uint4 v1 = tab[(size_t)s1 * 8 + c4];
            const uint4 v2 = tab[(size_t)s2 * 8 + c4];
            const uint4 v3 = tab[(size_t)s3 * 8 + c4];
            ACC8(v0); ACC8(v1); ACC8(v2); ACC8(v3);
            s0 = t0; s1 = t1; s2 = t2; s3 = t3;
        }
        const uint4 v0 = tab[(size_t)s0 * 8 + c4];
        const uint4 v1 = tab[(size_t)s1 * 8 + c4];
        const uint4 v2 = tab[(size_t)s2 * 8 + c4];
        const uint4 v3 = tab[(size_t)s3 * 8 + c4];
        ACC8(v0); ACC8(v1); ACC8(v2); ACC8(v3);
        i += 4;
    }
    for (; i + 4 <= dg; i += 4) {
        const int s0 = esrc[beg + i], s1 = esrc[beg + i + 1],
                  s2 = esrc[beg + i + 2], s3 = esrc[beg + i + 3];
        const uint4 v0 = tab[(size_t)s0 * 8 + c4];
        const uint4 v1 = tab[(size_t)s1 * 8 + c4];
        const uint4 v2 = tab[(size_t)s2 * 8 + c4];
        const uint4 v3 = tab[(size_t)s3 * 8 + c4];
        ACC8(v0); ACC8(v1); ACC8(v2); ACC8(v3);
    }
    for (; i < dg; ++i) {
        const uint4 v = tab[(size_t)esrc[beg + i] * 8 + c4];
        ACC8(v);
    }

    const float dv = dinv[node];
    const uint4 sv = tab[(size_t)node * 8 + c4];
    const float2 f0 = up2(sv.x), f1 = up2(sv.y), f2 = up2(sv.z), f3 = up2(sv.w);
    const float4 bb0 = ((const float4*)b1)[c4 * 2];
    const float4 bb1 = ((const float4*)b1)[c4 * 2 + 1];
    uint4 o;
    o.x = pk2(fmaxf(dv * (a[0] + f0.x) + bb0.x, 0.0f),
              fmaxf(dv * (a[1] + f0.y) + bb0.y, 0.0f));
    o.y = pk2(fmaxf(dv * (a[2] + f1.x) + bb0.z, 0.0f),
              fmaxf(dv * (a[3] + f1.y) + bb0.w, 0.0f));
    o.z = pk2(fmaxf(dv * (a[4] + f2.x) + bb1.x, 0.0f),
              fmaxf(dv * (a[5] + f2.y) + bb1.y, 0.0f));
    o.w = pk2(fmaxf(dv * (a[6] + f3.x) + bb1.z, 0.0f),
              fmaxf(dv * (a[7] + f3.y) + bb1.w, 0.0f));
    ((uint4*)z1h)[(size_t)node * 8 + c4] = o;
}

// ---------------- gemm2: g2h = half((z1h @ W2) * dinv) ----------------

__global__ __launch_bounds__(256) void gemm2_kernel(
    const __half* __restrict__ z1h, const float* __restrict__ W2,
    const float* __restrict__ dinv, __half* __restrict__ g2h, int n_nodes) {
    __shared__ float Wl[64 * 32];
    const int tid = threadIdx.x;
    {
        const float4* Ws = (const float4*)W2;
        float4* Wd = (float4*)Wl;
        Wd[tid] = Ws[tid];
        Wd[tid + 256] = Ws[tid + 256];
    }
    __syncthreads();

    const int tx = tid & 7;
    const int ty = tid >> 3;
    const int c0 = tx * 4;
    const int n0 = blockIdx.x * 128 + ty * 4;

    const uint2* xr[4];
#pragma unroll
    for (int nn = 0; nn < 4; ++nn) {
        const int node = n0 + nn;
        xr[nn] = (const uint2*)(z1h + (size_t)(node < n_nodes ? node : 0) * 64);
    }

    float acc[4][4] = {};
#pragma unroll 4
    for (int k4 = 0; k4 < 16; ++k4) {
        float4 wv[4];
#pragma unroll
        for (int kk = 0; kk < 4; ++kk)
            wv[kk] = *(const float4*)&Wl[(k4 * 4 + kk) * 32 + c0];
#pragma unroll
        for (int nn = 0; nn < 4; ++nn) {
            const uint2 xv = xr[nn][k4];
            const float2 xlo = up2(xv.x), xhi = up2(xv.y);
            acc[nn][0] = fmaf(xlo.x, wv[0].x, fmaf(xlo.y, wv[1].x, fmaf(xhi.x, wv[2].x, fmaf(xhi.y, wv[3].x, acc[nn][0]))));
            acc[nn][1] = fmaf(xlo.x, wv[0].y, fmaf(xlo.y, wv[1].y, fmaf(xhi.x, wv[2].y, fmaf(xhi.y, wv[3].y, acc[nn][1]))));
            acc[nn][2] = fmaf(xlo.x, wv[0].z, fmaf(xlo.y, wv[1].z, fmaf(xhi.x, wv[2].z, fmaf(xhi.y, wv[3].z, acc[nn][2]))));
            acc[nn][3] = fmaf(xlo.x, wv[0].w, fmaf(xlo.y, wv[1].w, fmaf(xhi.x, wv[2].w, fmaf(xhi.y, wv[3].w, acc[nn][3]))));
        }
    }

#pragma unroll
    for (int nn = 0; nn < 4; ++nn) {
        const int node = n0 + nn;
        if (node < n_nodes) {
            const float dv = dinv[node];
            uint2 o;
            o.x = pk2(acc[nn][0] * dv, acc[nn][1] * dv);
            o.y = pk2(acc[nn][2] * dv, acc[nn][3] * dv);
            *(uint2*)&g2h[(size_t)node * 32 + c0] = o;
        }
    }
}

// ---------------- agg32 + gemm3: g3 = (relu(...) . W3) * dinv ----------
// 4 lanes per node (16 consecutive nodes/wave); lane owns 8 channels (uint4).

__global__ __launch_bounds__(256) void agg32_gemm3_kernel(
    const int* __restrict__ row_start, const int* __restrict__ deg,
    const unsigned short* __restrict__ esrc, const __half* __restrict__ g2h,
    const float* __restrict__ dinv, const float* __restrict__ b2,
    const float* __restrict__ W3, float* __restrict__ g3, int n) {
    const int t = threadIdx.x;
    const int lane = t & 63;
    const int c2 = lane & 3;                 // uint4 slice within row
    const int node = blockIdx.x * 64 + (t >> 6) * 16 + (lane >> 2);
    if (node >= n) return;
    const uint4* __restrict__ tab = (const uint4*)g2h;   // 4 uint4 per row
    const int beg = row_start[node];
    const int dg = deg[node];

    float a[8] = {};
    int i = 0;
    if (dg >= 8) {
        int s0 = esrc[beg], s1 = esrc[beg + 1], s2 = esrc[beg + 2], s3 = esrc[beg + 3];
        for (; i + 8 <= dg; i += 4) {
            const int t0 = esrc[beg + i + 4], t1 = esrc[beg + i + 5],
                      t2 = esrc[beg + i + 6], t3 = esrc[beg + i + 7];
            const uint4 v0 = tab[(size_t)s0 * 4 + c2];
            const uint4 v1 = tab[(size_t)s1 * 4 + c2];
            const uint4 v2 = tab[(size_t)s2 * 4 + c2];
            const uint4 v3 = tab[(size_t)s3 * 4 + c2];
            ACC8(v0); ACC8(v1); ACC8(v2); ACC8(v3);
            s0 = t0; s1 = t1; s2 = t2; s3 = t3;
        }
        const uint4 v0 = tab[(size_t)s0 * 4 + c2];
        const uint4 v1 = tab[(size_t)s1 * 4 + c2];
        const uint4 v2 = tab[(size_t)s2 * 4 + c2];
        const uint4 v3 = tab[(size_t)s3 * 4 + c2];
        ACC8(v0); ACC8(v1); ACC8(v2); ACC8(v3);
        i += 4;
    }
    for (; i + 4 <= dg; i += 4) {
        const int s0 = esrc[beg + i], s1 = esrc[beg + i + 1],
                  s2 = esrc[beg + i + 2], s3 = esrc[beg + i + 3];
        const uint4 v0 = tab[(size_t)s0 * 4 + c2];
        const uint4 v1 = tab[(size_t)s1 * 4 + c2];
        const uint4 v2 = tab[(size_t)s2 * 4 + c2];
        const uint4 v3 = tab[(size_t)s3 * 4 + c2];
        ACC8(v0); ACC8(v1); ACC8(v2); ACC8(v3);
    }
    for (; i < dg; ++i) {
        const uint4 v = tab[(size_t)esrc[beg + i] * 4 + c2];
        ACC8(v);
    }

    const float dv = dinv[node];
    const uint4 sv = tab[(size_t)node * 4 + c2];
    const float2 f0 = up2(sv.x), f1 = up2(sv.y), f2 = up2(sv.z), f3 = up2(sv.w);
    const float4 bb0 = ((const float4*)b2)[c2 * 2];
    const float4 bb1 = ((const float4*)b2)[c2 * 2 + 1];
    const float4 w0 = ((const float4*)W3)[c2 * 2];
    const float4 w1 = ((const float4*)W3)[c2 * 2 + 1];
    float p = 0.0f;
    p = fmaf(fmaxf(dv * (a[0] + f0.x) + bb0.x, 0.0f), w0.x, p);
    p = fmaf(fmaxf(dv * (a[1] + f0.y) + bb0.y, 0.0f), w0.y, p);
    p = fmaf(fmaxf(dv * (a[2] + f1.x) + bb0.z, 0.0f), w0.z, p);
    p = fmaf(fmaxf(dv * (a[3] + f1.y) + bb0.w, 0.0f), w0.w, p);
    p = fmaf(fmaxf(dv * (a[4] + f2.x) + bb1.x, 0.0f), w1.x, p);
    p = fmaf(fmaxf(dv * (a[5] + f2.y) + bb1.y, 0.0f), w1.y, p);
    p = fmaf(fmaxf(dv * (a[6] + f3.x) + bb1.z, 0.0f), w1.z, p);
    p = fmaf(fmaxf(dv * (a[7] + f3.y) + bb1.w, 0.0f), w1.w, p);
    p += __shfl_xor(p, 1);
    p += __shfl_xor(p, 2);
    if (c2 == 0) g3[node] = p * dv;
}

// ---------------- layer-3 aggregation ----------------

__global__ __launch_bounds__(256) void agg_kernel1(
    const int* __restrict__ row_start, const int* __restrict__ deg,
    const unsigned short* __restrict__ esrc, const float* __restrict__ g,
    const float* __restrict__ dinv, const float* __restrict__ b3,
    float* __restrict__ out, int n) {
    const int node = blockIdx.x * 32 + (threadIdx.x >> 3);
    if (node >= n) return;
    const int l = threadIdx.x & 7;
    const int beg = row_start[node], end = beg + deg[node];
    float acc = 0.0f;
    for (int e = beg + l; e < end; e += 8)
        acc += g[esrc[e]];
    acc += __shfl_xor(acc, 1);
    acc += __shfl_xor(acc, 2);
    acc += __shfl_xor(acc, 4);
    if (l == 0) out[node] = dinv[node] * (acc + g[node]) + b3[0];
}

// ---------------- launcher ----------------

extern "C" void kernel_launch(void* const* d_in, const int* in_sizes, int n_in,
                              void* d_out, int out_size, void* d_ws, size_t ws_size,
                              hipStream_t stream) {
    const float* x  = (const float*)d_in[0];
    const int*   ei = (const int*)d_in[1];
    const float* W1 = (const float*)d_in[2];
    const float* b1 = (const float*)d_in[3];
    const float* W2 = (const float*)d_in[4];
    const float* b2 = (const float*)d_in[5];
    const float* W3 = (const float*)d_in[6];
    const float* b3 = (const float*)d_in[7];
    float* out = (float*)d_out;

    const int n_nodes = in_sizes[0] / IN_C;    // 50000
    const int n_edges = in_sizes[1] / 2;       // 800000
    const int* src = ei;
    const int* dst = ei + n_edges;
    const int nbuckets = (n_nodes + (1 << NPB_SHIFT) - 1) >> NPB_SHIFT;  // 196

    auto align_up = [](size_t v) { return (v + 255) & ~(size_t)255; };
    char* p = (char*)d_ws;
    int*            bucketcur = (int*)p;            p += align_up(256 * 4);
    int*            row_start = (int*)p;            p += align_up((size_t)n_nodes * 4);
    int*            deg       = (int*)p;            p += align_up((size_t)n_nodes * 4);
    float*          dinv      = (float*)p;          p += align_up((size_t)n_nodes * 4);
    unsigned short* esrc      = (unsigned short*)p; p += align_up((size_t)nbuckets * BCAP * 2);
    __half*         g1h       = (__half*)p;         p += align_up((size_t)n_nodes * 64 * 2);
    __half*         z1h       = (__half*)p;         p += align_up((size_t)n_nodes * 64 * 2);
    // union region: tmp (CSR build only) overlaid by g2h/g3 (layers 2/3)
    char* up = p;
    unsigned*       tmp       = (unsigned*)up;      // nbuckets*BCAP*4 ~ 4MB
    __half*         g2h       = (__half*)up;        // 3.2 MB
    float*          g3        = (float*)(up + align_up((size_t)n_nodes * 32 * 2));
    (void)ws_size; (void)n_in; (void)out_size;

    // CSR build (bucketed, no global scan)
    zero256_kernel<<<1, 256, 0, stream>>>(bucketcur);
    partition_kernel<<<(n_edges + 2047) / 2048, 256, 0, stream>>>(src, dst, bucketcur, tmp, n_edges, nbuckets);
    local_fill_kernel<<<nbuckets, 256, 0, stream>>>(tmp, bucketcur, row_start, deg, dinv, esrc, n_nodes);

    // layer 1: 128 -> 64 (g1h), agg (shuffle-free) -> z1h, dense gemm2 -> g2h
    gemm1_kernel<<<(n_nodes + 63) / 64, 256, 0, stream>>>(x, W1, dinv, g1h, n_nodes);
    agg64_kernel<<<(n_nodes + 31) / 32, 256, 0, stream>>>(row_start, deg, esrc, g1h, dinv, b1, z1h, n_nodes);
    gemm2_kernel<<<(n_nodes + 127) / 128, 256, 0, stream>>>(z1h, W2, dinv, g2h, n_nodes);

    // layer 2: agg (shuffle-free) + relu + dot(W3) -> g3
    agg32_gemm3_kernel<<<(n_nodes + 63) / 64, 256, 0, stream>>>(row_start, deg, esrc, g2h, dinv, b2, W3, g3, n_nodes);

    // layer 3: aggregate g3 -> out
    agg_kernel1<<<(n_nodes + 31) / 32, 256, 0, stream>>>(row_start, deg, esrc, g3, dinv, b3, out, n_nodes);
}